// Round 18
// baseline (144.360 us; speedup 1.0000x reference)
//
#include <hip/hip_runtime.h>
#include <hip/hip_bf16.h>
#include <math.h>

#define NCC 64
#define CSC 64
#define DC 64
#define S 72            // bf16 LDS row stride (144 B rows)
#define EPSF 1e-6f
#define LDS_BYTES 66816

typedef __attribute__((ext_vector_type(8))) short bf16x8;   // MFMA A/B frag
typedef __attribute__((ext_vector_type(4))) float f32x4;    // MFMA C/D frag
typedef __attribute__((ext_vector_type(4))) short short4v;
typedef __attribute__((ext_vector_type(2))) short short2v;

static __device__ __forceinline__ short cvt_bf16(float x) { // HW RNE
    union { __hip_bfloat16 b; short s; } u;
    u.b = __float2bfloat16(x);
    return u.s;
}
static __device__ __forceinline__ float bf16_to_f(unsigned hw) {
    union { unsigned u; float f; } v; v.u = hw << 16;
    return v.f;
}

// Barrier that drains ONLY LDS (lgkmcnt); global loads/stores stay in flight.
// Safe: all inter-wave communication is via LDS; global accesses are
// wave-private prefetches or write-only output.
static __device__ __forceinline__ void soft_barrier() {
    asm volatile("s_waitcnt lgkmcnt(0)" ::: "memory");
    __builtin_amdgcn_s_barrier();
}

// 16-lane sum via DPP row rotations (VALU-only; DPP row = 16 lanes).
#define DPP_ROR_ADD(v, N)                                                     \
    do {                                                                      \
        union { float f; int i; } _u, _r;                                     \
        _u.f = (v);                                                           \
        _r.i = __builtin_amdgcn_mov_dpp(_u.i, 0x120 + (N), 0xF, 0xF, true);   \
        (v) += _r.f;                                                          \
    } while (0)

static __device__ __forceinline__ float red16(float v) {
    DPP_ROR_ADD(v, 1);
    DPP_ROR_ADD(v, 2);
    DPP_ROR_ADD(v, 4);
    DPP_ROR_ADD(v, 8);
    return v;
}

__global__ __launch_bounds__(512, 1) void ttt_kernel(
    const float* __restrict__ xk, const float* __restrict__ xv,
    const float* __restrict__ weight, const float* __restrict__ bias,
    const float* __restrict__ gamma, const float* __restrict__ beta,
    const float* __restrict__ theta, const float* __restrict__ theta_bias,
    const float* __restrict__ alpha, float* __restrict__ out)
{
    extern __shared__ char sb[];
    auto xs_rm = (short (*)[CSC][S])(sb);             // [2][64][S] xk row-major
    auto xsT   = (short (*)[DC][S]) (sb + 18432);     // [2][64][S] xk^T (A of dW, epi xk)
    auto gsT   = (short (*)[S])     (sb + 36864);     // gs^T (B of dW and out)
    auto Gr    = (short (*)[S])     (sb + 46080);     // -(Gram+1) (ones-trick)
    auto Wtb   = (short (*)[S])     (sb + 55296);     // W [e][d] (B of z)
    auto dbp   = (float (*)[DC])    (sb + 64512);     // [8][64] db partials
    auto bs    = (float*)           (sb + 66560);     // [64] bias state, bs[4*la+n]=b[16n+la]

    const int t   = threadIdx.x;
    const int w   = t >> 6;           // wave 0..7
    const bool lo = (w < 4);          // state half vs output half
    const int ws  = w & 3;            // band within half
    const int l   = t & 63;
    const int g   = l >> 4, la = l & 15;
    const int r0  = 16*ws + 4*g;      // first row of this thread's C-frag
    const int io  = lo ? 0 : 2;       // epilogue row pair offset
    const int ts  = 64*ws + l;        // per-half thread id 0..255
    const int bh  = blockIdx.x;       // 0..63
    const int h   = bh & 15;

    const size_t bh_off = (size_t)bh * NCC*CSC*DC;
    const float* xkb = xk + bh_off;
    const float* xvb = xv + bh_off;
    float*       ob  = out + bh_off;

    // constants (both halves)
    float gam[4], bet[4], thv[4];
#pragma unroll
    for (int n = 0; n < 4; ++n) {
        gam[n] = gamma[h*DC + 16*n + la];
        bet[n] = beta [h*DC + 16*n + la];
        thv[n] = theta[h*DC + 16*n + la];
    }
    const float tb = theta_bias[h];
    float tokk[2];
#pragma unroll
    for (int ii = 0; ii < 2; ++ii) {
        int r = r0 + io + ii;
        tokk[ii] = fmaxf(1.0f/(float)(r+1) + alpha[r], 0.0f);
    }
    // bias state: bs[4*la'+n'] = bias[16n'+la']
    if (t < DC) bs[t] = bias[h*DC + 16*(t & 3) + (t >> 2)];

    float Wreg[4][4];                 // lo: W state
    float4 xl[4];                     // hi: xs_rm staging regs
    float xkh[4][4];                  // lo: xsT staging rows
    float xvg[2][4];                  // epilogue xv rows (both halves)

#pragma unroll
    for (int ii = 0; ii < 2; ++ii)
#pragma unroll
        for (int n = 0; n < 4; ++n)
            xvg[ii][n] = xvb[(r0+io+ii)*DC + 16*n + la];

    if (lo) {
        const float* wg = weight + h*DC*DC;
#pragma unroll
        for (int i = 0; i < 4; ++i)
#pragma unroll
            for (int n = 0; n < 4; ++n)
                Wreg[i][n] = wg[(r0+i)*DC + 16*n + la];
#pragma unroll
        for (int n = 0; n < 4; ++n) {
            short4v sv;
#pragma unroll
            for (int i = 0; i < 4; ++i) sv[i] = cvt_bf16(Wreg[i][n]);
            *(short4v*)&Wtb[16*n + la][r0] = sv;
        }
#pragma unroll
        for (int i = 0; i < 4; ++i)
#pragma unroll
            for (int n = 0; n < 4; ++n)
                xkh[i][n] = xkb[(r0+i)*DC + 16*n + la];
#pragma unroll
        for (int n = 0; n < 4; ++n) {       // stage chunk 0 transposed
            short4v sv;
#pragma unroll
            for (int i = 0; i < 4; ++i) sv[i] = cvt_bf16(xkh[i][n]);
            *(short4v*)&xsT[0][16*n + la][r0] = sv;
        }
    } else {
#pragma unroll
        for (int i4 = 0; i4 < 4; ++i4) xl[i4] = ((const float4*)xkb)[ts + 256*i4];
#pragma unroll
        for (int i4 = 0; i4 < 4; ++i4) {    // stage chunk 0 row-major
            int f = ts + 256*i4, k = f >> 4, j = f & 15;
            short4v s4;
            s4[0]=cvt_bf16(xl[i4].x); s4[1]=cvt_bf16(xl[i4].y);
            s4[2]=cvt_bf16(xl[i4].z); s4[3]=cvt_bf16(xl[i4].w);
            *(short4v*)&xs_rm[0][k][4*j] = s4;
        }
    }
    __syncthreads();

    for (int c = 0; c < NCC; ++c) {
        const int cb = c & 1, nb = cb ^ 1;
        const bool pf = (c + 1 < NCC);

        // b_old for this chunk (DS latency hidden under z MFMAs)
        f32x4 bold = *(const f32x4*)&bs[4*la];

        // ---- P1: z = xs@W (all waves) ----
        const bf16x8 a0 = *(const bf16x8*)&xs_rm[cb][16*ws + la][8*g];
        const bf16x8 a1 = *(const bf16x8*)&xs_rm[cb][16*ws + la][32 + 8*g];
        f32x4 zt[4];
#pragma unroll
        for (int n = 0; n < 4; ++n) {
            bf16x8 w0 = *(const bf16x8*)&Wtb[16*n + la][8*g];
            bf16x8 w1 = *(const bf16x8*)&Wtb[16*n + la][32 + 8*g];
            f32x4 zz = {0.f,0.f,0.f,0.f};
            zz = __builtin_amdgcn_mfma_f32_16x16x32_bf16(a0, w0, zz, 0,0,0);
            zz = __builtin_amdgcn_mfma_f32_16x16x32_bf16(a1, w1, zz, 0,0,0);
            zt[n] = zz;
        }
        if (!lo) {                    // -(Gram+1) (ones-trick) on high half
#pragma unroll
            for (int n = 0; n < 4; ++n) {
                bf16x8 b0 = *(const bf16x8*)&xs_rm[cb][16*n + la][8*g];
                bf16x8 b1 = *(const bf16x8*)&xs_rm[cb][16*n + la][32 + 8*g];
                f32x4 cc = {0.f,0.f,0.f,0.f};
                cc = __builtin_amdgcn_mfma_f32_16x16x32_bf16(a0, b0, cc, 0,0,0);
                cc = __builtin_amdgcn_mfma_f32_16x16x32_bf16(a1, b1, cc, 0,0,0);
                short4v sg;
#pragma unroll
                for (int i = 0; i < 4; ++i) sg[i] = cvt_bf16(-(cc[i] + 1.0f));
                *(short4v*)&Gr[16*n + la][r0] = sg;
            }
        }

        // epilogue xk rows from xsT (b32, conflict-free)
        float xkq[2][4];
#pragma unroll
        for (int n = 0; n < 4; ++n) {
            unsigned pk = *(const unsigned*)&xsT[cb][16*n + la][r0 + io];
            xkq[0][n] = bf16_to_f(pk & 0xFFFFu);
            xkq[1][n] = bf16_to_f(pk >> 16);
        }

        // VMEM prefetch for chunk c+1 (latency spans epilogue + barrier)
        float xvN[2][4];
        if (pf) {
            const float* xvn = xvb + (c+1)*CSC*DC;
#pragma unroll
            for (int ii = 0; ii < 2; ++ii)
#pragma unroll
                for (int n = 0; n < 4; ++n)
                    xvN[ii][n] = xvn[(r0+io+ii)*DC + 16*n + la];
            if (lo) {
                const float* xkn = xkb + (c+1)*CSC*DC;
#pragma unroll
                for (int i = 0; i < 4; ++i)
#pragma unroll
                    for (int n = 0; n < 4; ++n)
                        xkh[i][n] = xkn[(r0+i)*DC + 16*n + la];
            } else {
                const float* xkn = xkb + (c+1)*CSC*DC;
#pragma unroll
                for (int i4 = 0; i4 < 4; ++i4) xl[i4] = ((const float4*)xkn)[ts + 256*i4];
            }
        }

        // select this half's 2 epilogue rows
        float zrow[2][4];
        if (lo) {
#pragma unroll
            for (int n = 0; n < 4; ++n) { zrow[0][n] = zt[n][0]; zrow[1][n] = zt[n][1]; }
        } else {
#pragma unroll
            for (int n = 0; n < 4; ++n) { zrow[0][n] = zt[n][2]; zrow[1][n] = zt[n][3]; }
        }

        // ---- epilogue: 2 rows/thread, all 8 waves ----
        float gsv[2][4];
#pragma unroll
        for (int ii = 0; ii < 2; ++ii) {
            float z4[4];
#pragma unroll
            for (int n = 0; n < 4; ++n) z4[n] = zrow[ii][n] + bold[n];
            float szz = red16(z4[0]*z4[0] + z4[1]*z4[1] + z4[2]*z4[2] + z4[3]*z4[3]);
            float sz  = red16(z4[0] + z4[1] + z4[2] + z4[3]);
            float thd = red16(xkq[ii][0]*thv[0] + xkq[ii][1]*thv[1] +
                              xkq[ii][2]*thv[2] + xkq[ii][3]*thv[3]);
            float mu   = sz * (1.0f/DC);
            float var  = szz*(1.0f/DC) - mu*mu;
            float rstd = rsqrtf(var + EPSF);
            float ex   = __expf(-(thd + tb));
            float lr   = __builtin_amdgcn_rcpf(1.0f + ex);
            float eta  = tokk[ii]*lr*(1.0f/DC);
            float xh[4], gxh[4], a1v = 0.f, a2v = 0.f;
#pragma unroll
            for (int n = 0; n < 4; ++n) {
                xh[n] = (z4[n]-mu)*rstd;
                float y  = fmaf(gam[n], xh[n], bet[n]);
                float go = y - xvg[ii][n] + xkq[ii][n];
                gxh[n] = go*gam[n];
                a1v += gxh[n];
                a2v = fmaf(gxh[n], xh[n], a2v);
            }
            float s1 = red16(a1v), s2 = red16(a2v);
            float sc = rstd*(1.0f/DC)*eta;
#pragma unroll
            for (int n = 0; n < 4; ++n)
                gsv[ii][n] = (64.f*gxh[n] - s1 - xh[n]*s2)*sc;
        }
#pragma unroll
        for (int n = 0; n < 4; ++n) {       // gsT b32 pack (2 rows)
            short2v sg;
            sg[0] = cvt_bf16(gsv[0][n]);
            sg[1] = cvt_bf16(gsv[1][n]);
            *(short2v*)&gsT[16*n + la][r0 + io] = sg;
        }
        float dbl[4];
#pragma unroll
        for (int n = 0; n < 4; ++n) {       // per-wave db partial
            float dd = gsv[0][n] + gsv[1][n];
            dd += __shfl_xor(dd, 16);
            dd += __shfl_xor(dd, 32);
            dbl[n] = dd;
        }
        if (l < 16) {
            f32x4 dv = {dbl[0], dbl[1], dbl[2], dbl[3]};
            *(f32x4*)&dbp[w][4*la] = dv;
        }
        soft_barrier();    // B: gsT, Gr, dbp ready (LDS drain only)

        if (lo) {
            // ---- P2-low: dW + W update + Wtb + xsT staging + bias (w0) ----
            const bf16x8 ax0 = *(const bf16x8*)&xsT[cb][16*ws + la][8*g];
            const bf16x8 ax1 = *(const bf16x8*)&xsT[cb][16*ws + la][32 + 8*g];
#pragma unroll
            for (int n = 0; n < 4; ++n) {
                bf16x8 q0 = *(const bf16x8*)&gsT[16*n + la][8*g];
                bf16x8 q1 = *(const bf16x8*)&gsT[16*n + la][32 + 8*g];
                f32x4 dw = {0.f,0.f,0.f,0.f};
                dw = __builtin_amdgcn_mfma_f32_16x16x32_bf16(ax0, q0, dw, 0,0,0);
                dw = __builtin_amdgcn_mfma_f32_16x16x32_bf16(ax1, q1, dw, 0,0,0);
                short4v sw;
#pragma unroll
                for (int i = 0; i < 4; ++i) {
                    Wreg[i][n] -= dw[i];
                    sw[i] = cvt_bf16(Wreg[i][n]);
                }
                *(short4v*)&Wtb[16*n + la][r0] = sw;
            }
            if (pf) {                       // stage chunk c+1 transposed
#pragma unroll
                for (int n = 0; n < 4; ++n) {
                    short4v sv;
#pragma unroll
                    for (int i = 0; i < 4; ++i) sv[i] = cvt_bf16(xkh[i][n]);
                    *(short4v*)&xsT[nb][16*n + la][r0] = sv;
                }
            }
            if (w == 0) {                   // bias state update (wave 0 only)
                float s = dbp[0][l];
#pragma unroll
                for (int p = 1; p < 8; ++p) s += dbp[p][l];
                bs[l] -= s;
            }
        } else {
            // ---- P2-high: out = z + (-(G+1))@gs + b_old, then xs_rm staging ----
            const bf16x8 ar0 = *(const bf16x8*)&Gr[16*ws + la][8*g];
            const bf16x8 ar1 = *(const bf16x8*)&Gr[16*ws + la][32 + 8*g];
            float* oc = ob + c*CSC*DC;
#pragma unroll
            for (int n = 0; n < 4; ++n) {
                bf16x8 q0 = *(const bf16x8*)&gsT[16*n + la][8*g];
                bf16x8 q1 = *(const bf16x8*)&gsT[16*n + la][32 + 8*g];
                f32x4 og = zt[n];
                og = __builtin_amdgcn_mfma_f32_16x16x32_bf16(ar0, q0, og, 0,0,0);
                og = __builtin_amdgcn_mfma_f32_16x16x32_bf16(ar1, q1, og, 0,0,0);
#pragma unroll
                for (int i = 0; i < 4; ++i)
                    oc[(r0+i)*DC + 16*n + la] = og[i] + bold[n];
            }
            if (pf) {                       // stage chunk c+1 row-major
#pragma unroll
                for (int i4 = 0; i4 < 4; ++i4) {
                    int f = ts + 256*i4, k = f >> 4, j = f & 15;
                    short4v s4;
                    s4[0]=cvt_bf16(xl[i4].x); s4[1]=cvt_bf16(xl[i4].y);
                    s4[2]=cvt_bf16(xl[i4].z); s4[3]=cvt_bf16(xl[i4].w);
                    *(short4v*)&xs_rm[nb][k][4*j] = s4;
                }
            }
        }
        if (pf) {
#pragma unroll
            for (int ii = 0; ii < 2; ++ii)
#pragma unroll
                for (int n = 0; n < 4; ++n)
                    xvg[ii][n] = xvN[ii][n];
        }
        soft_barrier();    // C: Wtb, staged buffers, bs ready (LDS drain only)
    }
}

extern "C" void kernel_launch(void* const* d_in, const int* in_sizes, int n_in,
                              void* d_out, int out_size, void* d_ws, size_t ws_size,
                              hipStream_t stream) {
    const float* xk         = (const float*)d_in[0];
    const float* xv         = (const float*)d_in[1];
    const float* weight     = (const float*)d_in[2];
    const float* bias       = (const float*)d_in[3];
    const float* gamma      = (const float*)d_in[4];
    const float* beta       = (const float*)d_in[5];
    const float* theta      = (const float*)d_in[6];
    const float* theta_bias = (const float*)d_in[7];
    const float* alpha      = (const float*)d_in[8];
    float* out = (float*)d_out;

    (void)hipFuncSetAttribute((const void*)ttt_kernel,
                              hipFuncAttributeMaxDynamicSharedMemorySize,
                              LDS_BYTES);
    ttt_kernel<<<64, 512, LDS_BYTES, stream>>>(xk, xv, weight, bias, gamma, beta,
                                               theta, theta_bias, alpha, out);
}

// Round 19
// 140.236 us; speedup vs baseline: 1.0294x; 1.0294x over previous
//
#include <hip/hip_runtime.h>
#include <hip/hip_bf16.h>
#include <math.h>

#define NCC 64
#define CSC 64
#define DC 64
#define S 72            // bf16 LDS row stride (144 B rows)
#define EPSF 1e-6f
#define LDS_BYTES 66816

typedef __attribute__((ext_vector_type(8))) short bf16x8;   // MFMA A/B frag
typedef __attribute__((ext_vector_type(4))) float f32x4;    // MFMA C/D frag
typedef __attribute__((ext_vector_type(4))) short short4v;
typedef __attribute__((ext_vector_type(2))) short short2v;

static __device__ __forceinline__ short cvt_bf16(float x) { // HW RNE
    union { __hip_bfloat16 b; short s; } u;
    u.b = __float2bfloat16(x);
    return u.s;
}
static __device__ __forceinline__ float bf16_to_f(unsigned hw) {
    union { unsigned u; float f; } v; v.u = hw << 16;
    return v.f;
}

// Barrier that drains ONLY LDS (lgkmcnt), leaving global loads/stores in
// flight. Safe here: all inter-wave communication is via LDS; global accesses
// are wave-private prefetches or write-only output.
static __device__ __forceinline__ void soft_barrier() {
    asm volatile("s_waitcnt lgkmcnt(0)" ::: "memory");
    __builtin_amdgcn_s_barrier();
}

// 16-lane sum via DPP row rotations (VALU-only; DPP row = 16 lanes).
#define DPP_ROR_ADD(v, N)                                                     \
    do {                                                                      \
        union { float f; int i; } _u, _r;                                     \
        _u.f = (v);                                                           \
        _r.i = __builtin_amdgcn_mov_dpp(_u.i, 0x120 + (N), 0xF, 0xF, true);   \
        (v) += _r.f;                                                          \
    } while (0)

static __device__ __forceinline__ float red16(float v) {
    DPP_ROR_ADD(v, 1);
    DPP_ROR_ADD(v, 2);
    DPP_ROR_ADD(v, 4);
    DPP_ROR_ADD(v, 8);
    return v;
}

__global__ __launch_bounds__(512, 1) void ttt_kernel(
    const float* __restrict__ xk, const float* __restrict__ xv,
    const float* __restrict__ weight, const float* __restrict__ bias,
    const float* __restrict__ gamma, const float* __restrict__ beta,
    const float* __restrict__ theta, const float* __restrict__ theta_bias,
    const float* __restrict__ alpha, float* __restrict__ out)
{
    extern __shared__ char sb[];
    auto xs_rm = (short (*)[CSC][S])(sb);             // [2][64][S] xk row-major
    auto xsT   = (short (*)[DC][S]) (sb + 18432);     // [2][64][S] xk^T (A of dW, epi xk)
    auto gsT   = (short (*)[S])     (sb + 36864);     // gs^T (B of dW and out)
    auto Gr    = (short (*)[S])     (sb + 46080);     // -(Gram+1) (ones-trick)
    auto Wtb   = (short (*)[S])     (sb + 55296);     // W [e][d] (B of z)
    auto dbp   = (float (*)[DC])    (sb + 64512);     // [8][64] db partials
    auto bs    = (float*)           (sb + 66560);     // [64] bias state, bs[4*la+n]=b[16n+la]

    const int t   = threadIdx.x;
    const int w   = t >> 6;           // wave 0..7
    const bool lo = (w < 4);          // state half vs output half
    const int ws  = w & 3;            // band within half
    const int l   = t & 63;
    const int g   = l >> 4, la = l & 15;
    const int r0  = 16*ws + 4*g;      // first row of this thread's C-frag
    const int io  = lo ? 0 : 2;       // epilogue row pair offset
    const int ts  = 64*ws + l;        // per-half thread id 0..255
    const int bh  = blockIdx.x;       // 0..63
    const int h   = bh & 15;

    const size_t bh_off = (size_t)bh * NCC*CSC*DC;
    const float* xkb = xk + bh_off;
    const float* xvb = xv + bh_off;
    float*       ob  = out + bh_off;

    // constants (both halves)
    float gam[4], bet[4], thv[4];
#pragma unroll
    for (int n = 0; n < 4; ++n) {
        gam[n] = gamma[h*DC + 16*n + la];
        bet[n] = beta [h*DC + 16*n + la];
        thv[n] = theta[h*DC + 16*n + la];
    }
    const float tb = theta_bias[h];
    float tokk[2];
#pragma unroll
    for (int ii = 0; ii < 2; ++ii) {
        int r = r0 + io + ii;
        tokk[ii] = fmaxf(1.0f/(float)(r+1) + alpha[r], 0.0f);
    }
    // bias state: bs[4*la'+n'] = bias[16n'+la']
    if (t < DC) bs[t] = bias[h*DC + 16*(t & 3) + (t >> 2)];

    float Wreg[4][4];                 // low half: W state
    float4 xl[4];                     // low half: rm staging regs
    float xkh[4][4];                  // low half: xsT staging rows
    float xvg[2][4];                  // epilogue xv rows (both halves)

#pragma unroll
    for (int ii = 0; ii < 2; ++ii)
#pragma unroll
        for (int n = 0; n < 4; ++n)
            xvg[ii][n] = xvb[(r0+io+ii)*DC + 16*n + la];

    if (lo) {
        const float* wg = weight + h*DC*DC;
#pragma unroll
        for (int i = 0; i < 4; ++i)
#pragma unroll
            for (int n = 0; n < 4; ++n)
                Wreg[i][n] = wg[(r0+i)*DC + 16*n + la];
#pragma unroll
        for (int n = 0; n < 4; ++n) {
            short4v sv;
#pragma unroll
            for (int i = 0; i < 4; ++i) sv[i] = cvt_bf16(Wreg[i][n]);
            *(short4v*)&Wtb[16*n + la][r0] = sv;
        }
#pragma unroll
        for (int i4 = 0; i4 < 4; ++i4) xl[i4] = ((const float4*)xkb)[ts + 256*i4];
#pragma unroll
        for (int i = 0; i < 4; ++i)
#pragma unroll
            for (int n = 0; n < 4; ++n)
                xkh[i][n] = xkb[(r0+i)*DC + 16*n + la];
#pragma unroll
        for (int i4 = 0; i4 < 4; ++i4) {    // stage chunk 0 row-major
            int f = ts + 256*i4, k = f >> 4, j = f & 15;
            short4v s4;
            s4[0]=cvt_bf16(xl[i4].x); s4[1]=cvt_bf16(xl[i4].y);
            s4[2]=cvt_bf16(xl[i4].z); s4[3]=cvt_bf16(xl[i4].w);
            *(short4v*)&xs_rm[0][k][4*j] = s4;
        }
#pragma unroll
        for (int n = 0; n < 4; ++n) {       // stage chunk 0 transposed
            short4v sv;
#pragma unroll
            for (int i = 0; i < 4; ++i) sv[i] = cvt_bf16(xkh[i][n]);
            *(short4v*)&xsT[0][16*n + la][r0] = sv;
        }
    }
    __syncthreads();

    for (int c = 0; c < NCC; ++c) {
        const int cb = c & 1, nb = cb ^ 1;
        const bool pf = (c + 1 < NCC);

        // b_old for this chunk (DS latency hidden under z MFMAs)
        f32x4 bold = *(const f32x4*)&bs[4*la];

        // ---- P1: z = xs@W (all waves) ----
        const bf16x8 a0 = *(const bf16x8*)&xs_rm[cb][16*ws + la][8*g];
        const bf16x8 a1 = *(const bf16x8*)&xs_rm[cb][16*ws + la][32 + 8*g];
        f32x4 zt[4];
#pragma unroll
        for (int n = 0; n < 4; ++n) {
            bf16x8 w0 = *(const bf16x8*)&Wtb[16*n + la][8*g];
            bf16x8 w1 = *(const bf16x8*)&Wtb[16*n + la][32 + 8*g];
            f32x4 zz = {0.f,0.f,0.f,0.f};
            zz = __builtin_amdgcn_mfma_f32_16x16x32_bf16(a0, w0, zz, 0,0,0);
            zz = __builtin_amdgcn_mfma_f32_16x16x32_bf16(a1, w1, zz, 0,0,0);
            zt[n] = zz;
        }
        if (!lo) {                    // -(Gram+1) (ones-trick) on high half
#pragma unroll
            for (int n = 0; n < 4; ++n) {
                bf16x8 b0 = *(const bf16x8*)&xs_rm[cb][16*n + la][8*g];
                bf16x8 b1 = *(const bf16x8*)&xs_rm[cb][16*n + la][32 + 8*g];
                f32x4 cc = {0.f,0.f,0.f,0.f};
                cc = __builtin_amdgcn_mfma_f32_16x16x32_bf16(a0, b0, cc, 0,0,0);
                cc = __builtin_amdgcn_mfma_f32_16x16x32_bf16(a1, b1, cc, 0,0,0);
                short4v sg;
#pragma unroll
                for (int i = 0; i < 4; ++i) sg[i] = cvt_bf16(-(cc[i] + 1.0f));
                *(short4v*)&Gr[16*n + la][r0] = sg;
            }
        }

        // epilogue xk rows from xsT (b32, conflict-free)
        float xkq[2][4];
#pragma unroll
        for (int n = 0; n < 4; ++n) {
            unsigned pk = *(const unsigned*)&xsT[cb][16*n + la][r0 + io];
            xkq[0][n] = bf16_to_f(pk & 0xFFFFu);
            xkq[1][n] = bf16_to_f(pk >> 16);
        }

        // VMEM prefetch for chunk c+1 (latency spans epilogue + barrier)
        float xvN[2][4];
        if (pf) {
            const float* xvn = xvb + (c+1)*CSC*DC;
#pragma unroll
            for (int ii = 0; ii < 2; ++ii)
#pragma unroll
                for (int n = 0; n < 4; ++n)
                    xvN[ii][n] = xvn[(r0+io+ii)*DC + 16*n + la];
            if (lo) {
                const float* xkn = xkb + (c+1)*CSC*DC;
#pragma unroll
                for (int i4 = 0; i4 < 4; ++i4) xl[i4] = ((const float4*)xkn)[ts + 256*i4];
#pragma unroll
                for (int i = 0; i < 4; ++i)
#pragma unroll
                    for (int n = 0; n < 4; ++n)
                        xkh[i][n] = xkn[(r0+i)*DC + 16*n + la];
            }
        }

        // select this half's 2 epilogue rows
        float zrow[2][4];
        if (lo) {
#pragma unroll
            for (int n = 0; n < 4; ++n) { zrow[0][n] = zt[n][0]; zrow[1][n] = zt[n][1]; }
        } else {
#pragma unroll
            for (int n = 0; n < 4; ++n) { zrow[0][n] = zt[n][2]; zrow[1][n] = zt[n][3]; }
        }

        // ---- epilogue: 2 rows/thread, all 8 waves ----
        float gsv[2][4];
#pragma unroll
        for (int ii = 0; ii < 2; ++ii) {
            float z4[4];
#pragma unroll
            for (int n = 0; n < 4; ++n) z4[n] = zrow[ii][n] + bold[n];
            float szz = red16(z4[0]*z4[0] + z4[1]*z4[1] + z4[2]*z4[2] + z4[3]*z4[3]);
            float sz  = red16(z4[0] + z4[1] + z4[2] + z4[3]);
            float thd = red16(xkq[ii][0]*thv[0] + xkq[ii][1]*thv[1] +
                              xkq[ii][2]*thv[2] + xkq[ii][3]*thv[3]);
            float mu   = sz * (1.0f/DC);
            float var  = szz*(1.0f/DC) - mu*mu;
            float rstd = rsqrtf(var + EPSF);
            float ex   = __expf(-(thd + tb));
            float lr   = __builtin_amdgcn_rcpf(1.0f + ex);
            float eta  = tokk[ii]*lr*(1.0f/DC);
            float xh[4], gxh[4], a1v = 0.f, a2v = 0.f;
#pragma unroll
            for (int n = 0; n < 4; ++n) {
                xh[n] = (z4[n]-mu)*rstd;
                float y  = fmaf(gam[n], xh[n], bet[n]);
                float go = y - xvg[ii][n] + xkq[ii][n];
                gxh[n] = go*gam[n];
                a1v += gxh[n];
                a2v = fmaf(gxh[n], xh[n], a2v);
            }
            float s1 = red16(a1v), s2 = red16(a2v);
            float sc = rstd*(1.0f/DC)*eta;
#pragma unroll
            for (int n = 0; n < 4; ++n)
                gsv[ii][n] = (64.f*gxh[n] - s1 - xh[n]*s2)*sc;
        }
#pragma unroll
        for (int n = 0; n < 4; ++n) {       // gsT b32 pack (2 rows)
            short2v sg;
            sg[0] = cvt_bf16(gsv[0][n]);
            sg[1] = cvt_bf16(gsv[1][n]);
            *(short2v*)&gsT[16*n + la][r0 + io] = sg;
        }
        float dbl[4];
#pragma unroll
        for (int n = 0; n < 4; ++n) {       // per-wave db partial
            float dd = gsv[0][n] + gsv[1][n];
            dd += __shfl_xor(dd, 16);
            dd += __shfl_xor(dd, 32);
            dbl[n] = dd;
        }
        if (l < 16) {
            f32x4 dv = {dbl[0], dbl[1], dbl[2], dbl[3]};
            *(f32x4*)&dbp[w][4*la] = dv;
        }
        soft_barrier();    // B: gsT, Gr, dbp ready (LDS drain only)

        if (lo) {
            // ---- P2-low: dW + W update + Wtb + staging + bias (w0) ----
            const bf16x8 ax0 = *(const bf16x8*)&xsT[cb][16*ws + la][8*g];
            const bf16x8 ax1 = *(const bf16x8*)&xsT[cb][16*ws + la][32 + 8*g];
#pragma unroll
            for (int n = 0; n < 4; ++n) {
                bf16x8 q0 = *(const bf16x8*)&gsT[16*n + la][8*g];
                bf16x8 q1 = *(const bf16x8*)&gsT[16*n + la][32 + 8*g];
                f32x4 dw = {0.f,0.f,0.f,0.f};
                dw = __builtin_amdgcn_mfma_f32_16x16x32_bf16(ax0, q0, dw, 0,0,0);
                dw = __builtin_amdgcn_mfma_f32_16x16x32_bf16(ax1, q1, dw, 0,0,0);
                short4v sw;
#pragma unroll
                for (int i = 0; i < 4; ++i) {
                    Wreg[i][n] -= dw[i];
                    sw[i] = cvt_bf16(Wreg[i][n]);
                }
                *(short4v*)&Wtb[16*n + la][r0] = sw;
            }
            if (pf) {                       // stage chunk c+1
#pragma unroll
                for (int i4 = 0; i4 < 4; ++i4) {
                    int f = ts + 256*i4, k = f >> 4, j = f & 15;
                    short4v s4;
                    s4[0]=cvt_bf16(xl[i4].x); s4[1]=cvt_bf16(xl[i4].y);
                    s4[2]=cvt_bf16(xl[i4].z); s4[3]=cvt_bf16(xl[i4].w);
                    *(short4v*)&xs_rm[nb][k][4*j] = s4;
                }
#pragma unroll
                for (int n = 0; n < 4; ++n) {
                    short4v sv;
#pragma unroll
                    for (int i = 0; i < 4; ++i) sv[i] = cvt_bf16(xkh[i][n]);
                    *(short4v*)&xsT[nb][16*n + la][r0] = sv;
                }
            }
            if (w == 0) {                   // bias state update (wave 0 only)
                float s = dbp[0][l];
#pragma unroll
                for (int p = 1; p < 8; ++p) s += dbp[p][l];
                bs[l] -= s;
            }
        } else {
            // ---- P2-high: out = z + (-(G+1))@gs + b_old (acc into zt) ----
            const bf16x8 ar0 = *(const bf16x8*)&Gr[16*ws + la][8*g];
            const bf16x8 ar1 = *(const bf16x8*)&Gr[16*ws + la][32 + 8*g];
            float* oc = ob + c*CSC*DC;
#pragma unroll
            for (int n = 0; n < 4; ++n) {
                bf16x8 q0 = *(const bf16x8*)&gsT[16*n + la][8*g];
                bf16x8 q1 = *(const bf16x8*)&gsT[16*n + la][32 + 8*g];
                f32x4 og = zt[n];
                og = __builtin_amdgcn_mfma_f32_16x16x32_bf16(ar0, q0, og, 0,0,0);
                og = __builtin_amdgcn_mfma_f32_16x16x32_bf16(ar1, q1, og, 0,0,0);
#pragma unroll
                for (int i = 0; i < 4; ++i)
                    oc[(r0+i)*DC + 16*n + la] = og[i] + bold[n];
            }
        }
        if (pf) {
#pragma unroll
            for (int ii = 0; ii < 2; ++ii)
#pragma unroll
                for (int n = 0; n < 4; ++n)
                    xvg[ii][n] = xvN[ii][n];
        }
        soft_barrier();    // C: Wtb, staged buffers, bs ready (LDS drain only)
    }
}

extern "C" void kernel_launch(void* const* d_in, const int* in_sizes, int n_in,
                              void* d_out, int out_size, void* d_ws, size_t ws_size,
                              hipStream_t stream) {
    const float* xk         = (const float*)d_in[0];
    const float* xv         = (const float*)d_in[1];
    const float* weight     = (const float*)d_in[2];
    const float* bias       = (const float*)d_in[3];
    const float* gamma      = (const float*)d_in[4];
    const float* beta       = (const float*)d_in[5];
    const float* theta      = (const float*)d_in[6];
    const float* theta_bias = (const float*)d_in[7];
    const float* alpha      = (const float*)d_in[8];
    float* out = (float*)d_out;

    (void)hipFuncSetAttribute((const void*)ttt_kernel,
                              hipFuncAttributeMaxDynamicSharedMemorySize,
                              LDS_BYTES);
    ttt_kernel<<<64, 512, LDS_BYTES, stream>>>(xk, xv, weight, bias, gamma, beta,
                                               theta, theta_bias, alpha, out);
}